// Round 3
// baseline (170.555 us; speedup 1.0000x reference)
//
#include <hip/hip_runtime.h>
#include <stdint.h>

#define B_ROWS 32768
#define N_INP 256
#define N_HID 1024
#define NF 256
#define N_IT 100

typedef __attribute__((ext_vector_type(8))) _Float16 f16x8;
typedef __attribute__((ext_vector_type(4))) float f32x4;

__device__ __forceinline__ ushort f2h(float f) {
  _Float16 h = (_Float16)f;               // v_cvt_f16_f32, RNE
  return *reinterpret_cast<ushort*>(&h);
}

__device__ __forceinline__ void async_copy16(const void* g, void* l) {
  __builtin_amdgcn_global_load_lds(
      (const __attribute__((address_space(1))) void*)g,
      (__attribute__((address_space(3))) void*)l, 16, 0, 0);
}

// ---- prepass (fused): pack x -> f16 [B,256] + idx; convert W1/W2 -> f16 ----
__global__ void prep_kernel(const float* __restrict__ x,
                            const float* __restrict__ W1,
                            const float* __restrict__ W2,
                            ushort* __restrict__ xh,
                            ushort* __restrict__ w1h,
                            ushort* __restrict__ w2h,
                            int* __restrict__ idx) {
  if (blockIdx.x < 8192) {
    int t = blockIdx.x * 256 + threadIdx.x;          // B*64 threads
    int b = t >> 6, q = t & 63;
    const float* xr = x + (size_t)b * (N_INP + 1);
    float v0 = xr[q * 4 + 0], v1 = xr[q * 4 + 1], v2 = xr[q * 4 + 2], v3 = xr[q * 4 + 3];
    ushort4 u = make_ushort4(f2h(v0), f2h(v1), f2h(v2), f2h(v3));
    *reinterpret_cast<ushort4*>(xh + (size_t)b * 256 + q * 4) = u;
    if (q == 0) idx[b] = (int)rintf(xr[N_INP] * 255.0f);
  } else {
    int t = (blockIdx.x - 8192) * 256 + threadIdx.x; // 65536 threads
    float4 a = reinterpret_cast<const float4*>(W1)[t];
    float4 b = reinterpret_cast<const float4*>(W2)[t];
    reinterpret_cast<ushort4*>(w1h)[t] = make_ushort4(f2h(a.x), f2h(a.y), f2h(a.z), f2h(a.w));
    reinterpret_cast<ushort4*>(w2h)[t] = make_ushort4(f2h(b.x), f2h(b.y), f2h(b.z), f2h(b.w));
  }
}

// ---- C[M,N] = epi(A[M,K] @ Bw[N,K]^T + bias), f16 output ----
template <int RELU>
__global__ __launch_bounds__(256, 2) void gemm_bt(
    const ushort* __restrict__ A, const ushort* __restrict__ Bw,
    const float* __restrict__ bias, ushort* __restrict__ C,
    int M, int N, int K, int ntN) {
  __shared__ ushort As[2][128 * 64];
  __shared__ ushort Bs[2][128 * 64];
  const int tid = threadIdx.x;
  const int w = tid >> 6, l = tid & 63;
  const int tm = blockIdx.x / ntN, tn = blockIdx.x % ntN;
  const int wm = w >> 1, wn = w & 1;
  const char* Ab = (const char*)(A + (size_t)tm * 128 * K);
  const char* Bb = (const char*)(Bw + (size_t)tn * 128 * K);
  const int sA = K * 2;
  const int lrow = l >> 3;
  const int lcol = (l & 7) * 16;

  f32x4 acc[4][4];
#pragma unroll
  for (int i = 0; i < 4; ++i)
#pragma unroll
    for (int j = 0; j < 4; ++j) acc[i][j] = {0.f, 0.f, 0.f, 0.f};

  const int nkt = K / 64;
  {  // prologue stage kt=0
    const char* ga = Ab + lrow * sA + lcol;
    const char* gb = Bb + lrow * sA + lcol;
#pragma unroll
    for (int i = 0; i < 4; ++i) {
      int c = w * 4 + i;
      async_copy16(ga + c * 8 * sA, (char*)&As[0][0] + c * 1024);
      async_copy16(gb + c * 8 * sA, (char*)&Bs[0][0] + c * 1024);
    }
  }
  __syncthreads();

  const int arow = wm * 64 + (l & 15);
  const int brow = wn * 64 + (l & 15);
  const int koff = (l >> 4) * 8;

  for (int kt = 0; kt < nkt; ++kt) {
    const int buf = kt & 1;
    if (kt + 1 < nkt) {
      const char* ga = Ab + (kt + 1) * 128 + lrow * sA + lcol;
      const char* gb = Bb + (kt + 1) * 128 + lrow * sA + lcol;
#pragma unroll
      for (int i = 0; i < 4; ++i) {
        int c = w * 4 + i;
        async_copy16(ga + c * 8 * sA, (char*)&As[buf ^ 1][0] + c * 1024);
        async_copy16(gb + c * 8 * sA, (char*)&Bs[buf ^ 1][0] + c * 1024);
      }
    }
#pragma unroll
    for (int ks = 0; ks < 2; ++ks) {
      f16x8 af[4], bfr[4];
#pragma unroll
      for (int mi = 0; mi < 4; ++mi)
        af[mi] = *(const f16x8*)&As[buf][(arow + mi * 16) * 64 + ks * 32 + koff];
#pragma unroll
      for (int ni = 0; ni < 4; ++ni)
        bfr[ni] = *(const f16x8*)&Bs[buf][(brow + ni * 16) * 64 + ks * 32 + koff];
#pragma unroll
      for (int mi = 0; mi < 4; ++mi)
#pragma unroll
        for (int ni = 0; ni < 4; ++ni)
          acc[mi][ni] = __builtin_amdgcn_mfma_f32_16x16x32_f16(
              af[mi], bfr[ni], acc[mi][ni], 0, 0, 0);
    }
    __syncthreads();
  }

  const int grow0 = tm * 128 + wm * 64 + (l >> 4) * 4;
  const int gcol0 = tn * 128 + wn * 64 + (l & 15);
#pragma unroll
  for (int ni = 0; ni < 4; ++ni) {
    const int col = gcol0 + ni * 16;
    const float bv = bias[col];
#pragma unroll
    for (int mi = 0; mi < 4; ++mi) {
      const int row = grow0 + mi * 16;
#pragma unroll
      for (int r = 0; r < 4; ++r) {
        float v = acc[mi][ni][r] + bv;
        if (RELU) v = fmaxf(v, 0.f);
        C[(size_t)(row + r) * N + col] = f2h(v);
      }
    }
  }
}

// ---- convex fixed-point (100 iters) + gather ----
// y-space: y_i <- min(y_i, 0.5*(y_{i-1}+y_{i+1})); result = y.
// Layout: 4 lanes/row, 64 feats/lane in registers (static indexing).
// Jacobi via stride-8 blocks: compute m[] from old values, then min-assign.
// Only 2 shuffles per wave-iter serve 16 rows. Boundary feats via sentinels.
__global__ __launch_bounds__(256) void convex_gather(
    const ushort* __restrict__ xqh, const int* __restrict__ idx,
    float* __restrict__ out) {
  const int l = threadIdx.x & 63;
  const int wv = threadIdx.x >> 6;
  const int q = l & 3;                       // position of lane within row
  const int b = blockIdx.x * 64 + wv * 16 + (l >> 2);  // global row

  float y[64];
  {
    const ushort* src = xqh + (size_t)b * 256 + q * 64;
#pragma unroll
    for (int i = 0; i < 8; ++i) {
      f16x8 hv = *reinterpret_cast<const f16x8*>(src + i * 8);
#pragma unroll
      for (int j = 0; j < 8; ++j) y[i * 8 + j] = (float)hv[j];
    }
  }
  const int ii = idx[b];
  const float bL = (q == 0) ? 3.0e38f : 0.0f;  // feat 0 never drops
  const float bR = (q == 3) ? 3.0e38f : 0.0f;  // feat 255 never drops

  for (int it = 0; it < N_IT; ++it) {
    float Lv = __shfl_up(y[63], 1) + bL;   // old left neighbor of feat q*64
    float Rv = __shfl_down(y[0], 1) + bR;  // old right neighbor of feat q*64+63
    float prev = Lv;
#pragma unroll
    for (int blk = 0; blk < 8; ++blk) {
      float m[8];
#pragma unroll
      for (int t = 0; t < 8; ++t) {
        const int j = blk * 8 + t;
        float a = (t == 0) ? prev : y[j - 1];
        float c = (j == 63) ? Rv : y[j + 1];
        m[t] = 0.5f * (a + c);
      }
      prev = y[blk * 8 + 7];               // save old before overwrite
#pragma unroll
      for (int t = 0; t < 8; ++t) {
        const int j = blk * 8 + t;
        y[j] = fminf(y[j], m[t]);
      }
    }
  }

  // gather feature ii: binary cndmask tree over the 64 regs, then cross-lane pick
  const int sel = ii & 63;
#pragma unroll
  for (int step = 32; step >= 1; step >>= 1) {
#pragma unroll
    for (int k = 0; k < 32; ++k) {
      if (k < step) y[k] = (sel & step) ? y[k + step] : y[k];
    }
  }
  const int src_lane = (l & ~3) | (ii >> 6);
  float v = __shfl(y[0], src_lane);
  if (q == 0) out[b] = v;
}

extern "C" void kernel_launch(void* const* d_in, const int* in_sizes, int n_in,
                              void* d_out, int out_size, void* d_ws, size_t ws_size,
                              hipStream_t stream) {
  const float* x = (const float*)d_in[0];
  const float* W1 = (const float*)d_in[1];
  const float* b1 = (const float*)d_in[2];
  const float* W2 = (const float*)d_in[3];
  const float* b2 = (const float*)d_in[4];
  float* out = (float*)d_out;

  // workspace layout (16B-aligned)
  char* ws = (char*)d_ws;
  ushort* xh  = (ushort*)ws;                    // 16,777,216 B  x f16 [B,256]
  ushort* w1h = (ushort*)(ws + 16777216);       //    524,288 B
  ushort* w2h = (ushort*)(ws + 17301504);       //    524,288 B
  int*    idx = (int*)  (ws + 17825792);        //    131,072 B
  ushort* xqh = (ushort*)(ws + 17956864);       // 16,777,216 B  x_ f16 [B,256]
  ushort* h   = (ushort*)(ws + 34734080);       // chunk*2048 B  h f16 [chunk,1024]

  const size_t fixed = 34734080;
  int chunk = 2048;
  if (ws_size >= fixed + (size_t)32768 * 2048) chunk = 32768;
  else if (ws_size >= fixed + (size_t)16384 * 2048) chunk = 16384;
  else if (ws_size >= fixed + (size_t)8192 * 2048) chunk = 8192;
  else if (ws_size >= fixed + (size_t)4096 * 2048) chunk = 4096;

  prep_kernel<<<8448, 256, 0, stream>>>(x, W1, W2, xh, w1h, w2h, idx);

  for (int m0 = 0; m0 < B_ROWS; m0 += chunk) {
    int curM = (B_ROWS - m0 < chunk) ? (B_ROWS - m0) : chunk;
    dim3 g1((curM / 128) * (N_HID / 128));
    gemm_bt<1><<<g1, 256, 0, stream>>>(xh + (size_t)m0 * 256, w1h, b1, h,
                                       curM, N_HID, N_INP, N_HID / 128);
    dim3 g2((curM / 128) * (NF / 128));
    gemm_bt<0><<<g2, 256, 0, stream>>>(h, w2h, b2, xqh + (size_t)m0 * 256,
                                       curM, NF, N_HID, NF / 128);
  }
  convex_gather<<<B_ROWS / 64, 256, 0, stream>>>(xqh, idx, out);
}

// Round 4
// 146.095 us; speedup vs baseline: 1.1674x; 1.1674x over previous
//
#include <hip/hip_runtime.h>
#include <stdint.h>

#define B_ROWS 32768
#define N_INP 256
#define N_HID 1024
#define NF 256
#define N_IT 100

typedef __attribute__((ext_vector_type(8))) _Float16 f16x8;
typedef __attribute__((ext_vector_type(4))) float f32x4;

__device__ __forceinline__ ushort f2h(float f) {
  _Float16 h = (_Float16)f;               // v_cvt_f16_f32, RNE
  return *reinterpret_cast<ushort*>(&h);
}

__device__ __forceinline__ void async_copy16(const void* g, void* l) {
  __builtin_amdgcn_global_load_lds(
      (const __attribute__((address_space(1))) void*)g,
      (__attribute__((address_space(3))) void*)l, 16, 0, 0);
}

// ---- prepass (fused): pack x -> f16 [B,256] + idx; convert W1/W2 -> f16 ----
__global__ void prep_kernel(const float* __restrict__ x,
                            const float* __restrict__ W1,
                            const float* __restrict__ W2,
                            ushort* __restrict__ xh,
                            ushort* __restrict__ w1h,
                            ushort* __restrict__ w2h,
                            int* __restrict__ idx) {
  if (blockIdx.x < 8192) {
    int t = blockIdx.x * 256 + threadIdx.x;          // B*64 threads
    int b = t >> 6, q = t & 63;
    const float* xr = x + (size_t)b * (N_INP + 1);
    float v0 = xr[q * 4 + 0], v1 = xr[q * 4 + 1], v2 = xr[q * 4 + 2], v3 = xr[q * 4 + 3];
    ushort4 u = make_ushort4(f2h(v0), f2h(v1), f2h(v2), f2h(v3));
    *reinterpret_cast<ushort4*>(xh + (size_t)b * 256 + q * 4) = u;
    if (q == 0) idx[b] = (int)rintf(xr[N_INP] * 255.0f);
  } else {
    int t = (blockIdx.x - 8192) * 256 + threadIdx.x; // 65536 threads
    float4 a = reinterpret_cast<const float4*>(W1)[t];
    float4 b = reinterpret_cast<const float4*>(W2)[t];
    reinterpret_cast<ushort4*>(w1h)[t] = make_ushort4(f2h(a.x), f2h(a.y), f2h(a.z), f2h(a.w));
    reinterpret_cast<ushort4*>(w2h)[t] = make_ushort4(f2h(b.x), f2h(b.y), f2h(b.z), f2h(b.w));
  }
}

// ---- C[M,N] = epi(A[M,K] @ Bw[N,K]^T + bias), f16 output ----
template <int RELU>
__global__ __launch_bounds__(256, 2) void gemm_bt(
    const ushort* __restrict__ A, const ushort* __restrict__ Bw,
    const float* __restrict__ bias, ushort* __restrict__ C,
    int M, int N, int K, int ntN) {
  __shared__ ushort As[2][128 * 64];
  __shared__ ushort Bs[2][128 * 64];
  const int tid = threadIdx.x;
  const int w = tid >> 6, l = tid & 63;
  const int tm = blockIdx.x / ntN, tn = blockIdx.x % ntN;
  const int wm = w >> 1, wn = w & 1;
  const char* Ab = (const char*)(A + (size_t)tm * 128 * K);
  const char* Bb = (const char*)(Bw + (size_t)tn * 128 * K);
  const int sA = K * 2;
  const int lrow = l >> 3;
  const int lcol = (l & 7) * 16;

  f32x4 acc[4][4];
#pragma unroll
  for (int i = 0; i < 4; ++i)
#pragma unroll
    for (int j = 0; j < 4; ++j) acc[i][j] = {0.f, 0.f, 0.f, 0.f};

  const int nkt = K / 64;
  {  // prologue stage kt=0
    const char* ga = Ab + lrow * sA + lcol;
    const char* gb = Bb + lrow * sA + lcol;
#pragma unroll
    for (int i = 0; i < 4; ++i) {
      int c = w * 4 + i;
      async_copy16(ga + c * 8 * sA, (char*)&As[0][0] + c * 1024);
      async_copy16(gb + c * 8 * sA, (char*)&Bs[0][0] + c * 1024);
    }
  }
  __syncthreads();

  const int arow = wm * 64 + (l & 15);
  const int brow = wn * 64 + (l & 15);
  const int koff = (l >> 4) * 8;

  for (int kt = 0; kt < nkt; ++kt) {
    const int buf = kt & 1;
    if (kt + 1 < nkt) {
      const char* ga = Ab + (kt + 1) * 128 + lrow * sA + lcol;
      const char* gb = Bb + (kt + 1) * 128 + lrow * sA + lcol;
#pragma unroll
      for (int i = 0; i < 4; ++i) {
        int c = w * 4 + i;
        async_copy16(ga + c * 8 * sA, (char*)&As[buf ^ 1][0] + c * 1024);
        async_copy16(gb + c * 8 * sA, (char*)&Bs[buf ^ 1][0] + c * 1024);
      }
    }
#pragma unroll
    for (int ks = 0; ks < 2; ++ks) {
      f16x8 af[4], bfr[4];
#pragma unroll
      for (int mi = 0; mi < 4; ++mi)
        af[mi] = *(const f16x8*)&As[buf][(arow + mi * 16) * 64 + ks * 32 + koff];
#pragma unroll
      for (int ni = 0; ni < 4; ++ni)
        bfr[ni] = *(const f16x8*)&Bs[buf][(brow + ni * 16) * 64 + ks * 32 + koff];
#pragma unroll
      for (int mi = 0; mi < 4; ++mi)
#pragma unroll
        for (int ni = 0; ni < 4; ++ni)
          acc[mi][ni] = __builtin_amdgcn_mfma_f32_16x16x32_f16(
              af[mi], bfr[ni], acc[mi][ni], 0, 0, 0);
    }
    __syncthreads();
  }

  const int grow0 = tm * 128 + wm * 64 + (l >> 4) * 4;
  const int gcol0 = tn * 128 + wn * 64 + (l & 15);
#pragma unroll
  for (int ni = 0; ni < 4; ++ni) {
    const int col = gcol0 + ni * 16;
    const float bv = bias[col];
#pragma unroll
    for (int mi = 0; mi < 4; ++mi) {
      const int row = grow0 + mi * 16;
#pragma unroll
      for (int r = 0; r < 4; ++r) {
        float v = acc[mi][ni][r] + bv;
        if (RELU) v = fmaxf(v, 0.f);
        C[(size_t)(row + r) * N + col] = f2h(v);
      }
    }
  }
}

// ---- convex fixed-point (100 iters) + gather ----
// y-space: y_i <- min(y_i, 0.5*(y_{i-1}+y_{i+1})); result = y.
// Layout: 16 lanes/row, 16 feats/lane in registers (all static indices).
// 2 shuffles per wave-iter serve 4 rows; boundary feats via sentinels.
__global__ __launch_bounds__(256) void convex_gather(
    const ushort* __restrict__ xqh, const int* __restrict__ idx,
    float* __restrict__ out) {
  const int l = threadIdx.x & 63;
  const int wv = threadIdx.x >> 6;
  const int q = l & 15;                                // lane within row
  const int b = blockIdx.x * 16 + wv * 4 + (l >> 4);   // global row

  float y[16];
  {
    const ushort* src = xqh + (size_t)b * 256 + q * 16;
#pragma unroll
    for (int i = 0; i < 2; ++i) {
      f16x8 hv = *reinterpret_cast<const f16x8*>(src + i * 8);
#pragma unroll
      for (int j = 0; j < 8; ++j) y[i * 8 + j] = (float)hv[j];
    }
  }
  const int ii = idx[b];
  const float bL = (q == 0) ? 3.0e38f : 0.0f;   // feat 0 never drops
  const float bR = (q == 15) ? 3.0e38f : 0.0f;  // feat 255 never drops

  for (int it = 0; it < N_IT; ++it) {
    float Lv = __shfl_up(y[15], 1) + bL;   // old left neighbor of feat q*16
    float Rv = __shfl_down(y[0], 1) + bR;  // old right neighbor of feat q*16+15
    float m[8];
    // block 0: feats 0..7 (reads old y[0..8])
#pragma unroll
    for (int t = 0; t < 8; ++t) {
      float a = (t == 0) ? Lv : y[t - 1];
      m[t] = 0.5f * (a + y[t + 1]);
    }
    float prev = y[7];                     // save old y[7] for block 1
#pragma unroll
    for (int t = 0; t < 8; ++t) y[t] = fminf(y[t], m[t]);
    // block 1: feats 8..15 (reads old y[8..15] + prev + Rv)
#pragma unroll
    for (int t = 0; t < 8; ++t) {
      const int j = 8 + t;
      float a = (t == 0) ? prev : y[j - 1];
      float c = (j == 15) ? Rv : y[j + 1];
      m[t] = 0.5f * (a + c);
    }
#pragma unroll
    for (int t = 0; t < 8; ++t) y[8 + t] = fminf(y[8 + t], m[t]);
  }

  // gather feature ii: cndmask tree over 16 regs, then cross-lane pick
  const int sel = ii & 15;
#pragma unroll
  for (int step = 8; step >= 1; step >>= 1) {
#pragma unroll
    for (int k = 0; k < 8; ++k) {
      if (k < step) y[k] = (sel & step) ? y[k + step] : y[k];
    }
  }
  const int src_lane = (l & ~15) | (ii >> 4);
  float v = __shfl(y[0], src_lane);
  if (q == 0) out[b] = v;
}

extern "C" void kernel_launch(void* const* d_in, const int* in_sizes, int n_in,
                              void* d_out, int out_size, void* d_ws, size_t ws_size,
                              hipStream_t stream) {
  const float* x = (const float*)d_in[0];
  const float* W1 = (const float*)d_in[1];
  const float* b1 = (const float*)d_in[2];
  const float* W2 = (const float*)d_in[3];
  const float* b2 = (const float*)d_in[4];
  float* out = (float*)d_out;

  // workspace layout (16B-aligned)
  char* ws = (char*)d_ws;
  ushort* xh  = (ushort*)ws;                    // 16,777,216 B  x f16 [B,256]
  ushort* w1h = (ushort*)(ws + 16777216);       //    524,288 B
  ushort* w2h = (ushort*)(ws + 17301504);       //    524,288 B
  int*    idx = (int*)  (ws + 17825792);        //    131,072 B
  ushort* xqh = (ushort*)(ws + 17956864);       // 16,777,216 B  x_ f16 [B,256]
  ushort* h   = (ushort*)(ws + 34734080);       // chunk*2048 B  h f16 [chunk,1024]

  const size_t fixed = 34734080;
  int chunk = 2048;
  if (ws_size >= fixed + (size_t)32768 * 2048) chunk = 32768;
  else if (ws_size >= fixed + (size_t)16384 * 2048) chunk = 16384;
  else if (ws_size >= fixed + (size_t)8192 * 2048) chunk = 8192;
  else if (ws_size >= fixed + (size_t)4096 * 2048) chunk = 4096;

  prep_kernel<<<8448, 256, 0, stream>>>(x, W1, W2, xh, w1h, w2h, idx);

  for (int m0 = 0; m0 < B_ROWS; m0 += chunk) {
    int curM = (B_ROWS - m0 < chunk) ? (B_ROWS - m0) : chunk;
    dim3 g1((curM / 128) * (N_HID / 128));
    gemm_bt<1><<<g1, 256, 0, stream>>>(xh + (size_t)m0 * 256, w1h, b1, h,
                                       curM, N_HID, N_INP, N_HID / 128);
    dim3 g2((curM / 128) * (NF / 128));
    gemm_bt<0><<<g2, 256, 0, stream>>>(h, w2h, b2, xqh + (size_t)m0 * 256,
                                       curM, NF, N_HID, NF / 128);
  }
  convex_gather<<<B_ROWS / 16, 256, 0, stream>>>(xqh, idx, out);
}